// Round 10
// baseline (374.056 us; speedup 1.0000x reference)
//
#include <hip/hip_runtime.h>

#define NBATCH 4
#define NPTS   16384
#define BN     (NBATCH * NPTS)   // 65536 points

typedef __attribute__((ext_vector_type(8))) _Float16 half8;
typedef __attribute__((ext_vector_type(16))) float f32x16;

#define INV4096 2.44140625e-4f

// ---------- split-fp16 (hi + lo*2^-12 ~ fp32 accuracy) ----------
__device__ __forceinline__ void splith(float x, _Float16& h, _Float16& l) {
  float ax = __builtin_fabsf(x);
  if (ax < 6.1035e-5f) {
    unsigned short sb = (unsigned short)((__float_as_uint(x) >> 16) & 0x8000u);
    h = __builtin_bit_cast(_Float16, sb);          // +/-0 preserves sign for relu
    l = (_Float16)(x * 4096.f);
  } else {
    _Float16 hh = (_Float16)x;
    h = hh;
    l = (_Float16)((x - (float)hh) * 4096.f);      // x-hh exact (Sterbenz)
  }
}
__device__ __forceinline__ void splith8(const float v[8], half8& hi, half8& lo) {
  #pragma unroll
  for (int j = 0; j < 8; ++j) { _Float16 h, l; splith(v[j], h, l); hi[j] = h; lo[j] = l; }
}

// zero halves of v where the corresponding half of sgn has its sign bit set
__device__ __forceinline__ half8 relu8(half8 sgn, half8 v) {
  uint4 s = __builtin_bit_cast(uint4, sgn);
  uint4 x = __builtin_bit_cast(uint4, v);
  unsigned* sp = (unsigned*)&s;
  unsigned* xp = (unsigned*)&x;
  uint4 out;
  unsigned* op = (unsigned*)&out;
  #pragma unroll
  for (int w = 0; w < 4; ++w) {
    unsigned m = sp[w] & 0x80008000u;
    unsigned drop = (m - (m >> 15)) | m;   // 0xFFFF per negative half
    op[w] = xp[w] & ~drop;
  }
  return __builtin_bit_cast(half8, out);
}

// ---------- utility kernels ----------
__global__ void k_zero4(float4* __restrict__ p, int n4) {
  int g = blockIdx.x * 256 + threadIdx.x;
  if (g < n4) p[g] = make_float4(0.f, 0.f, 0.f, 0.f);
}

__device__ __forceinline__ int bin_of(const float* __restrict__ pts, int g) {
  float px = pts[g * 3 + 0], py = pts[g * 3 + 1];
  int xi = (int)(px * 128.f); xi = xi < 0 ? 0 : (xi > 127 ? 127 : xi);
  int yi = (int)(py * 128.f); yi = yi < 0 ? 0 : (yi > 127 ? 127 : yi);
  return xi + (yi << 7);
}

__global__ void k_idx(const float* __restrict__ pts, int* __restrict__ cnti) {
  int g = blockIdx.x * 256 + threadIdx.x;
  if (g >= BN) return;
  int b = g >> 14;
  atomicAdd(&cnti[(b << 14) + bin_of(pts, g)], 1);
}

// per-batch exclusive scan of cnti -> off (sorted start) and cursor
__global__ void k_scan(const int* __restrict__ cnti, int* __restrict__ off,
                       int* __restrict__ cursor) {
  __shared__ int part[256];
  const int b = blockIdx.x, t = threadIdx.x;
  const int base = b << 14;
  int s = 0;
  #pragma unroll 8
  for (int i = 0; i < 64; ++i) s += cnti[base + t * 64 + i];
  part[t] = s;
  __syncthreads();
  for (int o = 1; o < 256; o <<= 1) {
    int v = (t >= o) ? part[t - o] : 0;
    __syncthreads();
    part[t] += v;
    __syncthreads();
  }
  int run = base + (t == 0 ? 0 : part[t - 1]);
  #pragma unroll 8
  for (int i = 0; i < 64; ++i) {
    int g = base + t * 64 + i;
    off[g] = run;
    cursor[g] = run;
    run += cnti[g];
  }
}

__global__ void k_scatter(const float* __restrict__ pts, int* __restrict__ cursor,
                          int* __restrict__ perm, int* __restrict__ sbin) {
  int p = blockIdx.x * 256 + threadIdx.x;
  if (p >= BN) return;
  int b = p >> 14;
  int id = bin_of(pts, p);
  int pos = atomicAdd(&cursor[(b << 14) + id], 1);
  perm[pos] = p;
  sbin[pos] = id;
}

// ---------- pack weights into 32x32x16 frag-ordered split-fp16 planes ----------
// slot = (t*(K/16) + s)*64 + lane; holds 8 f16:
//   w[t*32 + (lane&31)][s*16 + (lane>>5)*8 + j]
__device__ __forceinline__ void pack_slot(const float* __restrict__ src, int K,
                                          _Float16* __restrict__ dhi, int NK,
                                          int slot) {
  int fpt = (K >> 4) << 6;                 // frags per 32-row tile
  int t = slot / fpt, rem = slot - t * fpt;
  int s = rem >> 6, lane = rem & 63;
  int row = (t << 5) + (lane & 31);
  int k0 = (s << 4) + ((lane >> 5) << 3);
  float v[8];
  #pragma unroll
  for (int j = 0; j < 8; ++j) v[j] = src[row * K + k0 + j];
  half8 hi, lo; splith8(v, hi, lo);
  *(half8*)&dhi[(size_t)slot << 3] = hi;
  *(half8*)&dhi[((size_t)slot << 3) + NK] = lo;
}

__global__ void k_pack(const float* __restrict__ fc0w, const float* __restrict__ scw,
                       const float* __restrict__ fc1w, const float* __restrict__ fccw,
                       _Float16* __restrict__ wp) {
  int g = blockIdx.x * 256 + threadIdx.x;
  if (g < 20480) {
    int l = g >> 12, slot = g & 4095;
    pack_slot(fc0w + (size_t)l * 32768, 256, wp + (size_t)l * 65536, 32768, slot);
  } else if (g < 40960) {
    int g2 = g - 20480; int l = g2 >> 12, slot = g2 & 4095;
    pack_slot(scw + (size_t)l * 32768, 256, wp + 327680 + (size_t)l * 65536, 32768, slot);
  } else if (g < 51200) {
    int g2 = g - 40960; int l = g2 >> 11, slot = g2 & 2047;
    pack_slot(fc1w + (size_t)l * 16384, 128, wp + 655360 + (size_t)l * 32768, 16384, slot);
  } else {
    int slot = g - 51200;
    pack_slot(fccw, 128, wp + 819200, 16384, slot);
  }
}

// ---------- fused ResnetBlockFC (32x32x16 MFMA, split-fp16), 32 sorted pts/block ----
// Pooling ON READ (segmented max over contiguous sorted rows of netIn).
// MODE 0: epilogue = plain store to netOut
// MODE 1: epilogue = fused fc_c GEMM + per-block segmented bin-sum -> atomicAdd(sums)
template <int SRC, int MODE>
__launch_bounds__(256, 4)
__global__ void k_rb(const float* __restrict__ pts, const float* __restrict__ netIn,
                     const int* __restrict__ perm, const int* __restrict__ sbin,
                     const int* __restrict__ off_, const int* __restrict__ cnti_,
                     const float* __restrict__ posw, const float* __restrict__ posb,
                     const _Float16* __restrict__ w0p, const float* __restrict__ b0,
                     const _Float16* __restrict__ w1p, const float* __restrict__ b1,
                     const _Float16* __restrict__ wsp,
                     float* __restrict__ netOut,
                     const _Float16* __restrict__ fccp, const float* __restrict__ fccb,
                     float* __restrict__ sums) {
  extern __shared__ _Float16 smem[];          // 32 KB
  _Float16* Ahi = smem;                       // 8192 f16 (16 chunks x 64 x 8)
  _Float16* Alo = smem + 8192;
  const int tid = threadIdx.x;
  const int lane = tid & 63, wave = tid >> 6;
  const int p0 = blockIdx.x << 5;             // 32 sorted points
  const int b = p0 >> 14;

  // ---- stage x (hi/lo 32x32x16-frag planes, XOR-swizzled) ----
  #pragma unroll
  for (int i = 0; i < 4; ++i) {
    int sidx = tid + (i << 8);                // 1024 slots
    int m = sidx >> 5, kslot = sidx & 31, k0 = kslot << 3;
    float v[8];
    if (SRC == 0) {
      const float* pp = &pts[(size_t)perm[p0 + m] * 3];
      float px = pp[0], py = pp[1], pz = pp[2];
      #pragma unroll
      for (int j = 0; j < 8; ++j) {
        int c = k0 + j;
        v[j] = fmaf(posw[c * 3 + 0], px,
               fmaf(posw[c * 3 + 1], py,
               fmaf(posw[c * 3 + 2], pz, posb[c])));
      }
    } else {
      if (kslot < 16) {
        float4 a = *(const float4*)&netIn[(size_t)(p0 + m) * 128 + k0];
        float4 c = *(const float4*)&netIn[(size_t)(p0 + m) * 128 + k0 + 4];
        v[0] = a.x; v[1] = a.y; v[2] = a.z; v[3] = a.w;
        v[4] = c.x; v[5] = c.y; v[6] = c.z; v[7] = c.w;
      } else {
        // pooled: max over this bin's contiguous rows (n >= 1), 2-way unrolled
        int g = (b << 14) + sbin[p0 + m];
        int s0 = off_[g], n = cnti_[g];
        const float* base = &netIn[(size_t)s0 * 128 + (k0 - 128)];
        float4 a = *(const float4*)base;
        float4 c = *(const float4*)(base + 4);
        int r = 1;
        for (; r + 1 < n; r += 2) {
          const float* r1 = base + (size_t)r * 128;
          const float* r2 = r1 + 128;
          float4 va = *(const float4*)r1;
          float4 vc = *(const float4*)(r1 + 4);
          float4 wa = *(const float4*)r2;
          float4 wc = *(const float4*)(r2 + 4);
          a.x = fmaxf(a.x, fmaxf(va.x, wa.x)); a.y = fmaxf(a.y, fmaxf(va.y, wa.y));
          a.z = fmaxf(a.z, fmaxf(va.z, wa.z)); a.w = fmaxf(a.w, fmaxf(va.w, wa.w));
          c.x = fmaxf(c.x, fmaxf(vc.x, wc.x)); c.y = fmaxf(c.y, fmaxf(vc.y, wc.y));
          c.z = fmaxf(c.z, fmaxf(vc.z, wc.z)); c.w = fmaxf(c.w, fmaxf(vc.w, wc.w));
        }
        if (r < n) {
          const float* rp = base + (size_t)r * 128;
          float4 va = *(const float4*)rp;
          float4 vc = *(const float4*)(rp + 4);
          a.x = fmaxf(a.x, va.x); a.y = fmaxf(a.y, va.y);
          a.z = fmaxf(a.z, va.z); a.w = fmaxf(a.w, va.w);
          c.x = fmaxf(c.x, vc.x); c.y = fmaxf(c.y, vc.y);
          c.z = fmaxf(c.z, vc.z); c.w = fmaxf(c.w, vc.w);
        }
        v[0] = a.x; v[1] = a.y; v[2] = a.z; v[3] = a.w;
        v[4] = c.x; v[5] = c.y; v[6] = c.z; v[7] = c.w;
      }
    }
    half8 hi, lo; splith8(v, hi, lo);
    // element (m, k0..k0+7): chunk kg = kslot>>1, frag-lane = (kslot&1)*32 + m
    int kg = kslot >> 1;
    int flane = ((kslot & 1) << 5) + m;
    int u = (kg << 6) + (flane ^ kg);
    *(half8*)&Ahi[u << 3] = hi;
    *(half8*)&Alo[u << 3] = lo;
  }
  __syncthreads();

  // ---- combined K-loop (K=256, 16 chunks): h = relu(x)@w0+b0 ; s = x@ws+b1 ----
  f32x16 hm, hc, so, sc;
  {
    float bv0 = b0[(wave << 5) + (lane & 31)];
    float bv1 = b1[(wave << 5) + (lane & 31)];
    #pragma unroll
    for (int r = 0; r < 16; ++r) { hm[r] = bv0; so[r] = bv1; hc[r] = 0.f; sc[r] = 0.f; }
  }
  const _Float16* w0lo = w0p + 32768;
  const _Float16* wslo = wsp + 32768;

  half8 c0h, c0l, csh, csl;
  {
    size_t fo = (((size_t)(wave << 4) << 6) + lane) << 3;   // tile=wave, ks=0
    c0h = *(const half8*)&w0p[fo];
    c0l = *(const half8*)&w0lo[fo];
    csh = *(const half8*)&wsp[fo];
    csl = *(const half8*)&wslo[fo];
  }
  #pragma unroll
  for (int ks = 0; ks < 16; ++ks) {
    half8 n0h, n0l, nsh, nsl;
    if (ks < 15) {
      size_t fo = (((size_t)((wave << 4) + ks + 1) << 6) + lane) << 3;
      n0h = *(const half8*)&w0p[fo];
      n0l = *(const half8*)&w0lo[fo];
      nsh = *(const half8*)&wsp[fo];
      nsl = *(const half8*)&wslo[fo];
    }
    int u = (ks << 6) + (lane ^ ks);
    half8 ah = *(const half8*)&Ahi[u << 3];
    half8 al = *(const half8*)&Alo[u << 3];
    half8 arh = relu8(ah, ah);
    half8 arl = relu8(ah, al);
    hm = __builtin_amdgcn_mfma_f32_32x32x16_f16(arh, c0h, hm, 0, 0, 0);
    hc = __builtin_amdgcn_mfma_f32_32x32x16_f16(arl, c0h, hc, 0, 0, 0);
    hc = __builtin_amdgcn_mfma_f32_32x32x16_f16(arh, c0l, hc, 0, 0, 0);
    so = __builtin_amdgcn_mfma_f32_32x32x16_f16(ah,  csh, so, 0, 0, 0);
    sc = __builtin_amdgcn_mfma_f32_32x32x16_f16(al,  csh, sc, 0, 0, 0);
    sc = __builtin_amdgcn_mfma_f32_32x32x16_f16(ah,  csl, sc, 0, 0, 0);
    if (ks < 15) { c0h = n0h; c0l = n0l; csh = nsh; csl = nsl; }
  }
  __syncthreads();   // x planes dead; overlay h frags

  // ---- write relu(h) into A2 frag planes (K2 = 128, 8 chunks) ----
  _Float16* A2hi = smem;                      // 4096 f16
  _Float16* A2lo = smem + 4096;
  {
    int col = lane & 31, hi5 = lane >> 5;
    #pragma unroll
    for (int r = 0; r < 16; ++r) {
      int m = (r & 3) + ((r >> 2) << 3) + (hi5 << 2);   // C-layout row
      float hv = fmaxf(fmaf(hc[r], INV4096, hm[r]), 0.f);
      _Float16 hb, lb; splith(hv, hb, lb);
      int n = (wave << 5) + col;              // h-channel = A2's K index
      int kg2 = n >> 4;
      int fl2 = (((n >> 3) & 1) << 5) + m;
      int u2 = (kg2 << 6) + (fl2 ^ kg2);
      int j2 = n & 7;
      A2hi[(u2 << 3) + j2] = hb;
      A2lo[(u2 << 3) + j2] = lb;
    }
  }
  __syncthreads();

  // ---- GEMM1: s += relu(h) @ w1 (K=128, 8 chunks) ----
  const _Float16* w1lo = w1p + 16384;
  half8 w1ch, w1cl;
  {
    size_t fo = (((size_t)(wave << 3) << 6) + lane) << 3;
    w1ch = *(const half8*)&w1p[fo];
    w1cl = *(const half8*)&w1lo[fo];
  }
  #pragma unroll
  for (int ks = 0; ks < 8; ++ks) {
    half8 nh, nl;
    if (ks < 7) {
      size_t fo = (((size_t)((wave << 3) + ks + 1) << 6) + lane) << 3;
      nh = *(const half8*)&w1p[fo];
      nl = *(const half8*)&w1lo[fo];
    }
    int u = (ks << 6) + (lane ^ ks);
    half8 ah = *(const half8*)&A2hi[u << 3];
    half8 al = *(const half8*)&A2lo[u << 3];
    so = __builtin_amdgcn_mfma_f32_32x32x16_f16(ah, w1ch, so, 0, 0, 0);
    sc = __builtin_amdgcn_mfma_f32_32x32x16_f16(al, w1ch, sc, 0, 0, 0);
    sc = __builtin_amdgcn_mfma_f32_32x32x16_f16(ah, w1cl, sc, 0, 0, 0);
    if (ks < 7) { w1ch = nh; w1cl = nl; }
  }

  if (MODE == 0) {
    // ---- epilogue A: plain store to netOut (sorted rows) ----
    int col = lane & 31, hi5 = lane >> 5;
    int n = (wave << 5) + col;
    #pragma unroll
    for (int r = 0; r < 16; ++r) {
      int m_g = p0 + (r & 3) + ((r >> 2) << 3) + (hi5 << 2);
      netOut[(size_t)m_g * 128 + n] = fmaf(sc[r], INV4096, so[r]);
    }
  } else {
    // ---- epilogue B: fused fc_c + segmented bin-sum ----
    float* S = (float*)smem;                    // 32 x 132 f32 tile (16.9 KB)
    int* Bid = (int*)((char*)smem + 16896);     // 32 bin ids
    __syncthreads();                          // all A2 reads (GEMM1) done
    {
      int col = lane & 31, hi5 = lane >> 5;
      #pragma unroll
      for (int r = 0; r < 16; ++r) {
        int m = (r & 3) + ((r >> 2) << 3) + (hi5 << 2);
        float sv = fmaxf(fmaf(sc[r], INV4096, so[r]), 0.f);
        _Float16 hb, lb; splith(sv, hb, lb);
        int n = (wave << 5) + col;
        int kg2 = n >> 4;
        int fl2 = (((n >> 3) & 1) << 5) + m;
        int u2 = (kg2 << 6) + (fl2 ^ kg2);
        int j2 = n & 7;
        A2hi[(u2 << 3) + j2] = hb;
        A2lo[(u2 << 3) + j2] = lb;
      }
    }
    __syncthreads();
    const _Float16* flo = fccp + 16384;
    f32x16 am, ac;
    {
      float bv = fccb[(wave << 5) + (lane & 31)];
      #pragma unroll
      for (int r = 0; r < 16; ++r) { am[r] = bv; ac[r] = 0.f; }
    }
    #pragma unroll
    for (int ks = 0; ks < 8; ++ks) {
      size_t fo = (((size_t)((wave << 3) + ks) << 6) + lane) << 3;
      half8 ch = *(const half8*)&fccp[fo];
      half8 cl = *(const half8*)&flo[fo];
      int u = (ks << 6) + (lane ^ ks);
      half8 ah = *(const half8*)&A2hi[u << 3];
      half8 al = *(const half8*)&A2lo[u << 3];
      am = __builtin_amdgcn_mfma_f32_32x32x16_f16(ah, ch, am, 0, 0, 0);
      ac = __builtin_amdgcn_mfma_f32_32x32x16_f16(al, ch, ac, 0, 0, 0);
      ac = __builtin_amdgcn_mfma_f32_32x32x16_f16(ah, cl, ac, 0, 0, 0);
    }
    __syncthreads();                          // all A2 reads done; reuse smem
    {
      int col = lane & 31, hi5 = lane >> 5;
      int n = (wave << 5) + col;
      #pragma unroll
      for (int r = 0; r < 16; ++r) {
        int mrow = (r & 3) + ((r >> 2) << 3) + (hi5 << 2);
        S[mrow * 132 + n] = fmaf(ac[r], INV4096, am[r]);
      }
      if (tid < 32) Bid[tid] = sbin[p0 + tid];
    }
    __syncthreads();
    {
      int c = tid & 127, h = (tid >> 7) << 4;
      int cur = Bid[h];
      float acc = S[h * 132 + c];
      #pragma unroll
      for (int m2 = 1; m2 < 16; ++m2) {
        int m = h + m2;
        int id = Bid[m];
        float e = S[m * 132 + c];
        if (id != cur) {
          atomicAdd(&sums[(size_t)(((b << 14) + cur) << 7) + c], acc);
          cur = id; acc = e;
        } else acc += e;
      }
      atomicAdd(&sums[(size_t)(((b << 14) + cur) << 7) + c], acc);
    }
  }
}

// ---------- divide by counts + transpose (B,R2,C) -> (B,C,R2) ----------
__launch_bounds__(256)
__global__ void k_finalize(const float* __restrict__ sums, const int* __restrict__ cnti,
                           float* __restrict__ out) {
  __shared__ float t[64 * 65];
  __shared__ float rc[64];
  const int bid = blockIdx.x;
  const int ct = bid & 1, rt = (bid >> 1) & 255, b = bid >> 9;
  const int r0 = rt << 6, c0 = ct << 6;
  const int tid = threadIdx.x, l16 = tid & 15, sl = tid >> 4;
  for (int rr = sl; rr < 64; rr += 16) {
    float4 v = *(const float4*)&sums[(size_t)((b << 14) + r0 + rr) * 128 + c0 + (l16 << 2)];
    int cb = l16 << 2;
    t[rr * 65 + cb + 0] = v.x; t[rr * 65 + cb + 1] = v.y;
    t[rr * 65 + cb + 2] = v.z; t[rr * 65 + cb + 3] = v.w;
  }
  if (tid < 64) rc[tid] = 1.f / fmaxf((float)cnti[(b << 14) + r0 + tid], 1.f);
  __syncthreads();
  for (int cc = sl; cc < 64; cc += 16) {
    int c = c0 + cc;
    int rb = l16 << 2;
    float4 o = make_float4(t[(rb + 0) * 65 + cc] * rc[rb + 0],
                           t[(rb + 1) * 65 + cc] * rc[rb + 1],
                           t[(rb + 2) * 65 + cc] * rc[rb + 2],
                           t[(rb + 3) * 65 + cc] * rc[rb + 3]);
    *(float4*)&out[(size_t)((b << 7) + c) * 16384 + r0 + rb] = o;
  }
}

// ---------- host launch ----------
extern "C" void kernel_launch(void* const* d_in, const int* in_sizes, int n_in,
                              void* d_out, int out_size, void* d_ws, size_t ws_size,
                              hipStream_t stream) {
  const float* points = (const float*)d_in[0];
  const float* posw   = (const float*)d_in[1];
  const float* posb   = (const float*)d_in[2];
  const float* fc0w   = (const float*)d_in[3];
  const float* fc0b   = (const float*)d_in[4];
  const float* fc1w   = (const float*)d_in[5];
  const float* fc1b   = (const float*)d_in[6];
  const float* scw    = (const float*)d_in[7];
  const float* fccw   = (const float*)d_in[8];
  const float* fccb   = (const float*)d_in[9];
  float* outp = (float*)d_out;

  // workspace: net_a 32MB | net_b 32MB | sort | packed weights  (~70 MB)
  float* net_a = (float*)d_ws;
  float* net_b = net_a + (size_t)BN * 128;
  int* perm   = (int*)(net_b + (size_t)BN * 128);
  int* sbin   = perm + BN;
  int* cnti   = sbin + BN;
  int* off    = cnti + BN;
  int* cursor = off + BN;
  _Float16* wp = (_Float16*)(cursor + BN);

  const _Float16* w0_ = wp;            // 5 x 65536 (hi|lo)
  const _Float16* ws_ = wp + 327680;   // 5 x 65536
  const _Float16* w1_ = wp + 655360;   // 5 x 32768
  const _Float16* fcc_ = wp + 819200;  // 32768

  k_zero4<<<64, 256, 0, stream>>>((float4*)cnti, 16384);
  k_idx<<<256, 256, 0, stream>>>(points, cnti);
  k_scan<<<4, 256, 0, stream>>>(cnti, off, cursor);
  k_scatter<<<256, 256, 0, stream>>>(points, cursor, perm, sbin);
  k_pack<<<208, 256, 0, stream>>>(fc0w, scw, fc1w, fccw, wp);

  // ping-pong: L0 -> a, L1: a->b, L2: b->a, L3: a->b, L4: b -> sums(=a)
  k_rb<0, 0><<<2048, 256, 32768, stream>>>(points, nullptr, perm, sbin, off, cnti,
                                           posw, posb,
                                           w0_, fc0b, w1_, fc1b, ws_, net_a,
                                           fcc_, fccb, nullptr);
  const float* src = net_a;
  float* dst = net_b;
  for (int l = 1; l < 4; ++l) {
    k_rb<1, 0><<<2048, 256, 32768, stream>>>(points, src, perm, sbin, off, cnti,
                                             posw, posb,
                                             w0_ + (size_t)l * 65536, fc0b + l * 128,
                                             w1_ + (size_t)l * 32768, fc1b + l * 128,
                                             ws_ + (size_t)l * 65536, dst,
                                             fcc_, fccb, nullptr);
    float* t = (float*)src; src = dst; dst = t;
  }
  // after L3: src = net_b (L3 output), dst = net_a (dead) -> reuse as sums
  float* sums = dst;
  k_zero4<<<8192, 256, 0, stream>>>((float4*)sums, 2097152);
  k_rb<1, 1><<<2048, 256, 32768, stream>>>(points, src, perm, sbin, off, cnti,
                                           posw, posb,
                                           w0_ + (size_t)4 * 65536, fc0b + 4 * 128,
                                           w1_ + (size_t)4 * 32768, fc1b + 4 * 128,
                                           ws_ + (size_t)4 * 65536, nullptr,
                                           fcc_, fccb, sums);
  k_finalize<<<2048, 256, 0, stream>>>(sums, cnti, outp);
}